// Round 1
// baseline (154.671 us; speedup 1.0000x reference)
//
#include <hip/hip_runtime.h>

namespace {

constexpr int B = 4, L = 4096, HC = 4, D = 1024, K = 4, DIL = 2;
constexpr int PAD = (K - 1) * DIL;       // 6
constexpr float EPS = 1e-5f;
constexpr int TL = 32;                   // output rows (L positions) per block
constexpr int NROWS = TL + PAD;          // 38 rows incl. causal halo
constexpr int NT = L / TL;               // 128 tiles along L
constexpr int BDIM = 256;                // 4 waves

struct R4 { float v[4]; };

__global__ __launch_bounds__(BDIM) void engram_shortconv_fused(
    const float* __restrict__ x,
    const float* __restrict__ nw,
    const float* __restrict__ cw,
    float* __restrict__ out)
{
    __shared__ float s_inv[NROWS];

    const int blk = blockIdx.x;
    const int t   = blk % NT;
    const int hc  = (blk / NT) % HC;
    const int b   = blk / (NT * HC);
    const int l0  = t * TL;
    const int r0  = l0 - PAD;

    const int tid  = threadIdx.x;
    const int wave = tid >> 6;
    const int lane = tid & 63;

    const size_t rowstride = (size_t)HC * D;   // floats between consecutive l
    const float* xb = x + ((size_t)b * L * HC + (size_t)hc) * D;

    // ---- Phase 1: inverse RMS per row, wave-per-row ----
    for (int r = wave; r < NROWS; r += BDIM / 64) {
        const int l = r0 + r;
        float inv = 0.0f;
        if (l >= 0) {
            const float* row = xb + (size_t)l * rowstride;
            float ss = 0.0f;
            #pragma unroll
            for (int j = 0; j < 4; ++j) {
                const float4 v = *(const float4*)(row + (lane + j * 64) * 4);
                ss += v.x * v.x + v.y * v.y + v.z * v.z + v.w * v.w;
            }
            #pragma unroll
            for (int off = 32; off >= 1; off >>= 1) ss += __shfl_xor(ss, off);
            inv = rsqrtf(ss * (1.0f / D) + EPS);
        }
        if (lane == 0) s_inv[r] = inv;
    }
    __syncthreads();

    // ---- Phase 2: dilated causal depthwise conv + SiLU ----
    // Each thread owns a float4 column group d..d+3 for all TL rows.
    const int d = tid * 4;
    const float4 nw4 = *(const float4*)(nw + (size_t)hc * D + d);
    const float nwv[4] = { nw4.x, nw4.y, nw4.z, nw4.w };

    float wk[4][4]; // [channel j][tap k]; conv_weight is [C,1,K] so taps contiguous
    #pragma unroll
    for (int j = 0; j < 4; ++j) {
        const float4 w = *(const float4*)(cw + ((size_t)hc * D + d + j) * K);
        wk[j][0] = w.x; wk[j][1] = w.y; wk[j][2] = w.z; wk[j][3] = w.w;
    }

    const float* xcol = xb + d;
    float* ocol = out + ((size_t)b * L * HC + (size_t)hc) * D + d;

    auto loadrow = [&](int l) -> R4 {
        R4 r;
        if (l >= 0) {
            const float4 v = *(const float4*)(xcol + (size_t)l * rowstride);
            r.v[0] = v.x; r.v[1] = v.y; r.v[2] = v.z; r.v[3] = v.w;
        } else {
            r.v[0] = r.v[1] = r.v[2] = r.v[3] = 0.0f;
        }
        return r;
    };

    // Two parity-separated sliding windows (taps are all same parity as l).
    R4 e1 = loadrow(l0 - 6), e2 = loadrow(l0 - 4), e3 = loadrow(l0 - 2);
    R4 o1 = loadrow(l0 - 5), o2 = loadrow(l0 - 3), o3 = loadrow(l0 - 1);
    R4 e0, o0;

    for (int i = 0; i < TL; i += 2) {
        // even output row l = l0 + i; taps rows l-6,l-4,l-2,l -> s_inv[i + 2k]
        e0 = e1; e1 = e2; e2 = e3; e3 = loadrow(l0 + i);
        {
            const float i0 = s_inv[i], i1 = s_inv[i + 2],
                        i2 = s_inv[i + 4], i3 = s_inv[i + 6];
            float4 o;
            float* op = &o.x;
            #pragma unroll
            for (int j = 0; j < 4; ++j) {
                float a = wk[j][0] * e0.v[j] * i0 + wk[j][1] * e1.v[j] * i1
                        + wk[j][2] * e2.v[j] * i2 + wk[j][3] * e3.v[j] * i3;
                a *= nwv[j];
                op[j] = a / (1.0f + __expf(-a));
            }
            *(float4*)(ocol + (size_t)(l0 + i) * rowstride) = o;
        }
        // odd output row l = l0 + i + 1; s_inv[(i+1) + 2k]
        o0 = o1; o1 = o2; o2 = o3; o3 = loadrow(l0 + i + 1);
        {
            const float i0 = s_inv[i + 1], i1 = s_inv[i + 3],
                        i2 = s_inv[i + 5], i3 = s_inv[i + 7];
            float4 o;
            float* op = &o.x;
            #pragma unroll
            for (int j = 0; j < 4; ++j) {
                float a = wk[j][0] * o0.v[j] * i0 + wk[j][1] * o1.v[j] * i1
                        + wk[j][2] * o2.v[j] * i2 + wk[j][3] * o3.v[j] * i3;
                a *= nwv[j];
                op[j] = a / (1.0f + __expf(-a));
            }
            *(float4*)(ocol + (size_t)(l0 + i + 1) * rowstride) = o;
        }
    }
}

} // namespace

extern "C" void kernel_launch(void* const* d_in, const int* in_sizes, int n_in,
                              void* d_out, int out_size, void* d_ws, size_t ws_size,
                              hipStream_t stream) {
    const float* x  = (const float*)d_in[0];   // [B, L, HC, D] f32
    const float* nw = (const float*)d_in[1];   // [HC, D] f32
    const float* cw = (const float*)d_in[2];   // [C, 1, K] f32
    float* out = (float*)d_out;                // [B, L, HC, D] f32

    const int nblocks = B * HC * NT;           // 2048
    engram_shortconv_fused<<<dim3(nblocks), dim3(BDIM), 0, stream>>>(x, nw, cw, out);
}

// Round 2
// 127.918 us; speedup vs baseline: 1.2091x; 1.2091x over previous
//
#include <hip/hip_runtime.h>

namespace {

constexpr int B = 4, L = 4096, HC = 4, D = 1024, K = 4, DIL = 2;
constexpr int PAD = (K - 1) * DIL;       // 6
constexpr float EPS = 1e-5f;
constexpr int TL = 32;                   // output rows per block
constexpr int NROWS = TL + PAD;          // 38 rows incl. causal halo
constexpr int NT = L / TL;               // 128 tiles along L
constexpr int BDIM = 256;                // 4 waves

__global__ __launch_bounds__(BDIM, 2) void engram_shortconv_regres(
    const float* __restrict__ x,
    const float* __restrict__ nw,
    const float* __restrict__ cw,
    float* __restrict__ out)
{
    __shared__ float s_part[NROWS][BDIM];   // 38 KiB per-thread square partials
    __shared__ float s_inv[NROWS];

    const int blk = blockIdx.x;
    const int t   = blk % NT;
    const int hc  = (blk / NT) % HC;
    const int b   = blk / (NT * HC);
    const int l0  = t * TL;
    const int r0  = l0 - PAD;

    const int tid  = threadIdx.x;
    const int wave = tid >> 6;
    const int lane = tid & 63;

    const size_t rowstride = (size_t)HC * D;
    const float* xb = x + ((size_t)b * L * HC + (size_t)hc) * D;
    const int d = tid * 4;
    const float* xcol = xb + d;
    float* ocol = out + ((size_t)b * L * HC + (size_t)hc) * D + d;

    // ---- per-channel weights ----
    const float4 nw4 = *(const float4*)(nw + (size_t)hc * D + d);
    const float nwv[4] = { nw4.x, nw4.y, nw4.z, nw4.w };
    float wk[4][4];   // [channel j][tap k]
    #pragma unroll
    for (int j = 0; j < 4; ++j) {
        const float4 w = *(const float4*)(cw + ((size_t)hc * D + d + j) * K);
        wk[j][0] = w.x; wk[j][1] = w.y; wk[j][2] = w.z; wk[j][3] = w.w;
    }

    // ---- single read: all 38 rows into registers (38 independent loads) ----
    float r[NROWS][4];
    if (r0 >= 0) {
        #pragma unroll
        for (int rr = 0; rr < NROWS; ++rr) {
            const float4 v = *(const float4*)(xcol + (size_t)(r0 + rr) * rowstride);
            r[rr][0] = v.x; r[rr][1] = v.y; r[rr][2] = v.z; r[rr][3] = v.w;
        }
    } else {
        #pragma unroll
        for (int rr = 0; rr < NROWS; ++rr) {
            const int l = r0 + rr;
            float4 v = make_float4(0.f, 0.f, 0.f, 0.f);
            if (l >= 0) v = *(const float4*)(xcol + (size_t)l * rowstride);
            r[rr][0] = v.x; r[rr][1] = v.y; r[rr][2] = v.z; r[rr][3] = v.w;
        }
    }

    // ---- per-thread square partials -> LDS ----
    #pragma unroll
    for (int rr = 0; rr < NROWS; ++rr) {
        s_part[rr][tid] = r[rr][0] * r[rr][0] + r[rr][1] * r[rr][1]
                        + r[rr][2] * r[rr][2] + r[rr][3] * r[rr][3];
    }
    __syncthreads();

    // ---- block reduction: wave-per-row ----
    for (int rr = wave; rr < NROWS; rr += BDIM / 64) {
        float s = s_part[rr][lane]       + s_part[rr][lane + 64]
                + s_part[rr][lane + 128] + s_part[rr][lane + 192];
        #pragma unroll
        for (int off = 32; off >= 1; off >>= 1) s += __shfl_xor(s, off);
        if (lane == 0) s_inv[rr] = rsqrtf(s * (1.0f / D) + EPS);
    }
    __syncthreads();

    // ---- conv + SiLU entirely from registers ----
    #pragma unroll
    for (int i = 0; i < TL; ++i) {
        const float i0 = s_inv[i],     i1 = s_inv[i + 2],
                    i2 = s_inv[i + 4], i3 = s_inv[i + 6];
        float4 o;
        float* op = &o.x;
        #pragma unroll
        for (int j = 0; j < 4; ++j) {
            float a = wk[j][0] * r[i][j]     * i0
                    + wk[j][1] * r[i + 2][j] * i1
                    + wk[j][2] * r[i + 4][j] * i2
                    + wk[j][3] * r[i + 6][j] * i3;
            a *= nwv[j];
            op[j] = a / (1.0f + __expf(-a));
        }
        *(float4*)(ocol + (size_t)(l0 + i) * rowstride) = o;
    }
}

} // namespace

extern "C" void kernel_launch(void* const* d_in, const int* in_sizes, int n_in,
                              void* d_out, int out_size, void* d_ws, size_t ws_size,
                              hipStream_t stream) {
    const float* x  = (const float*)d_in[0];   // [B, L, HC, D] f32
    const float* nw = (const float*)d_in[1];   // [HC, D] f32
    const float* cw = (const float*)d_in[2];   // [C, 1, K] f32
    float* out = (float*)d_out;                // [B, L, HC, D] f32

    const int nblocks = B * HC * NT;           // 2048
    engram_shortconv_regres<<<dim3(nblocks), dim3(BDIM), 0, stream>>>(x, nw, cw, out);
}

// Round 3
// 111.298 us; speedup vs baseline: 1.3897x; 1.1493x over previous
//
#include <hip/hip_runtime.h>

namespace {

constexpr int B = 4, L = 4096, HC = 4, D = 1024, K = 4, DIL = 2;
constexpr int PAD = (K - 1) * DIL;   // 6
constexpr float EPS = 1e-5f;
constexpr int CL = 64;               // rows per block (chunk)
constexpr int ST = 8;                // rows per step
constexpr int NSTEP = CL / ST;       // 8
constexpr int NT = L / CL;           // 64 chunks along L
constexpr int BDIM = 256;            // 4 waves

__global__ __launch_bounds__(BDIM, 4) void engram_shortconv_stream(
    const float* __restrict__ x,
    const float* __restrict__ nw,
    const float* __restrict__ cw,
    float* __restrict__ out)
{
    __shared__ float s_part[ST][BDIM];   // 8 KiB
    __shared__ float s_inv[CL + PAD];    // 70 entries

    const int blk = blockIdx.x;
    const int t   = blk % NT;
    const int hc  = (blk / NT) % HC;
    const int b   = blk / (NT * HC);
    const int l0  = t * CL;

    const int tid  = threadIdx.x;
    const int wave = tid >> 6;
    const int lane = tid & 63;

    const size_t rs = (size_t)HC * D;
    const float* xcol = x   + ((size_t)b * L * HC + (size_t)hc) * D + tid * 4;
    float*       ocol = out + ((size_t)b * L * HC + (size_t)hc) * D + tid * 4;

    // ---- weights, norm folded into conv taps ----
    const float4 nw4 = *(const float4*)(nw + (size_t)hc * D + tid * 4);
    const float nwv[4] = { nw4.x, nw4.y, nw4.z, nw4.w };
    float wk[4][4];   // [channel j][tap k], pre-multiplied by nw[j]
    #pragma unroll
    for (int j = 0; j < 4; ++j) {
        const float4 w = *(const float4*)(cw + ((size_t)hc * D + tid * 4 + j) * K);
        wk[j][0] = w.x * nwv[j]; wk[j][1] = w.y * nwv[j];
        wk[j][2] = w.z * nwv[j]; wk[j][3] = w.w * nwv[j];
    }

    float win[PAD][4];   // scaled halo rows (base-6 .. base-1)
    float pf[ST][4];     // current step rows (raw, then scaled in place)

    // ---- prologue: halo rows l0-6 .. l0-1 ----
    #pragma unroll
    for (int r = 0; r < PAD; ++r) {
        const int l = l0 - PAD + r;
        float4 v = make_float4(0.f, 0.f, 0.f, 0.f);
        if (l >= 0) v = *(const float4*)(xcol + (size_t)l * rs);
        win[r][0] = v.x; win[r][1] = v.y; win[r][2] = v.z; win[r][3] = v.w;
    }
    #pragma unroll
    for (int r = 0; r < PAD; ++r)
        s_part[r][tid] = win[r][0]*win[r][0] + win[r][1]*win[r][1]
                       + win[r][2]*win[r][2] + win[r][3]*win[r][3];
    // issue step-0 loads before the barrier (latency overlaps the reduce)
    #pragma unroll
    for (int r = 0; r < ST; ++r) {
        const float4 v = *(const float4*)(xcol + (size_t)(l0 + r) * rs);
        pf[r][0] = v.x; pf[r][1] = v.y; pf[r][2] = v.z; pf[r][3] = v.w;
    }
    __syncthreads();
    for (int rr = wave; rr < PAD; rr += 4) {
        float s = s_part[rr][lane]       + s_part[rr][lane + 64]
                + s_part[rr][lane + 128] + s_part[rr][lane + 192];
        #pragma unroll
        for (int off = 32; off >= 1; off >>= 1) s += __shfl_xor(s, off);
        if (lane == 0) s_inv[rr] = rsqrtf(s * (1.0f / D) + EPS);
    }
    __syncthreads();
    #pragma unroll
    for (int r = 0; r < PAD; ++r) {
        const float iv = s_inv[r];
        win[r][0] *= iv; win[r][1] *= iv; win[r][2] *= iv; win[r][3] *= iv;
    }

    // ---- steady steps ----
    for (int s = 0; s < NSTEP; ++s) {
        const int base = l0 + s * ST;
        const int ib   = s * ST + PAD;      // s_inv index of row `base`

        #pragma unroll
        for (int r = 0; r < ST; ++r)
            s_part[r][tid] = pf[r][0]*pf[r][0] + pf[r][1]*pf[r][1]
                           + pf[r][2]*pf[r][2] + pf[r][3]*pf[r][3];
        __syncthreads();
        for (int rr = wave; rr < ST; rr += 4) {
            float sm = s_part[rr][lane]       + s_part[rr][lane + 64]
                     + s_part[rr][lane + 128] + s_part[rr][lane + 192];
            #pragma unroll
            for (int off = 32; off >= 1; off >>= 1) sm += __shfl_xor(sm, off);
            if (lane == 0) s_inv[ib + rr] = rsqrtf(sm * (1.0f / D) + EPS);
        }
        __syncthreads();

        // scale current rows in place
        #pragma unroll
        for (int r = 0; r < ST; ++r) {
            const float iv = s_inv[ib + r];
            pf[r][0] *= iv; pf[r][1] *= iv; pf[r][2] *= iv; pf[r][3] *= iv;
        }

        // conv + SiLU + store: output row base+i uses taps rel = i-6+2k
        #pragma unroll
        for (int i = 0; i < ST; ++i) {
            float4 o; float* op = &o.x;
            #pragma unroll
            for (int j = 0; j < 4; ++j) {
                float a = 0.f;
                #pragma unroll
                for (int k = 0; k < 4; ++k) {
                    const int rel = i - 6 + 2 * k;
                    const float xv = (rel < 0) ? win[6 + rel][j] : pf[rel][j];
                    a = fmaf(wk[j][k], xv, a);
                }
                op[j] = a / (1.0f + __expf(-a));
            }
            *(float4*)(ocol + (size_t)(base + i) * rs) = o;
        }

        // rotate halo: new halo = rows base+2 .. base+7 (already scaled)
        #pragma unroll
        for (int r = 0; r < PAD; ++r) {
            win[r][0] = pf[r + 2][0]; win[r][1] = pf[r + 2][1];
            win[r][2] = pf[r + 2][2]; win[r][3] = pf[r + 2][3];
        }

        // issue next step's loads (one step of slack before first use)
        if (s < NSTEP - 1) {
            #pragma unroll
            for (int r = 0; r < ST; ++r) {
                const float4 v = *(const float4*)(xcol + (size_t)(base + ST + r) * rs);
                pf[r][0] = v.x; pf[r][1] = v.y; pf[r][2] = v.z; pf[r][3] = v.w;
            }
        }
    }
}

} // namespace

extern "C" void kernel_launch(void* const* d_in, const int* in_sizes, int n_in,
                              void* d_out, int out_size, void* d_ws, size_t ws_size,
                              hipStream_t stream) {
    const float* x  = (const float*)d_in[0];   // [B, L, HC, D] f32
    const float* nw = (const float*)d_in[1];   // [HC, D] f32
    const float* cw = (const float*)d_in[2];   // [C, 1, K] f32
    float* out = (float*)d_out;                // [B, L, HC, D] f32

    const int nblocks = B * HC * NT;           // 1024
    engram_shortconv_stream<<<dim3(nblocks), dim3(BDIM), 0, stream>>>(x, nw, cw, out);
}